// Round 4
// baseline (249.518 us; speedup 1.0000x reference)
//
#include <hip/hip_runtime.h>

// PredictionLatticeCore: the gate path (einsum + sigmoid) is algebraically
// dead — x_out = g*h + (1-g)*h == h. Output = x with spine rows replaced by
// layernorm(0.5*x[b,spine,:]) * ln_g + ln_b.
//
// Kernel 1: vectorized full copy x -> out (mandatory: d_out re-poisoned
//           to 0xAA before every timed call). Nontemporal hints: pure
//           stream, destination never re-read. Uses a native ext_vector
//           float4 — __builtin_nontemporal_* rejects HIP_vector_type.
// Kernel 2: B*K (=20) blocks, one per (b,k) spine row, two-pass LN,
//           overwrites the copied row (stream-ordered after the copy).

#define D_MODEL 2048
#define SEQ_LEN 8192
#define LN_EPS 1e-5f

typedef float f32x4 __attribute__((ext_vector_type(4)));

__global__ __launch_bounds__(256) void copy_kernel(const f32x4* __restrict__ in,
                                                   f32x4* __restrict__ out,
                                                   long n4) {
    long i = (long)blockIdx.x * blockDim.x + threadIdx.x;
    long stride = (long)gridDim.x * blockDim.x;
    for (; i < n4; i += stride) {
        f32x4 v = __builtin_nontemporal_load(&in[i]);
        __builtin_nontemporal_store(v, &out[i]);
    }
}

__global__ __launch_bounds__(256) void spine_ln_kernel(const float* __restrict__ x,
                                                       const float* __restrict__ ln_g,
                                                       const float* __restrict__ ln_b,
                                                       const int* __restrict__ spine,
                                                       float* __restrict__ out,
                                                       int K) {
    const int bk = blockIdx.x;          // b*K + k
    const int b = bk / K;
    const int k = bk - b * K;
    const long row_base = (long)b * ((long)SEQ_LEN * D_MODEL)
                        + (long)spine[k] * D_MODEL;

    const int t = threadIdx.x;          // 256 threads, 8 floats each (2x float4)
    const float4* xin = (const float4*)(x + row_base);

    float4 h[2];
    float sum = 0.f, ss = 0.f;
#pragma unroll
    for (int j = 0; j < 2; ++j) {
        float4 v = xin[t * 2 + j];
        v.x *= 0.5f; v.y *= 0.5f; v.z *= 0.5f; v.w *= 0.5f;
        h[j] = v;
        sum += v.x + v.y + v.z + v.w;
        ss  += v.x * v.x + v.y * v.y + v.z * v.z + v.w * v.w;
    }

    // wave (64-lane) butterfly reduce, then cross-wave via LDS (4 waves)
#pragma unroll
    for (int off = 32; off > 0; off >>= 1) {
        sum += __shfl_down(sum, off, 64);
        ss  += __shfl_down(ss,  off, 64);
    }
    __shared__ float s_sum[4];
    __shared__ float s_ss[4];
    const int wave = t >> 6;
    const int lane = t & 63;
    if (lane == 0) { s_sum[wave] = sum; s_ss[wave] = ss; }
    __syncthreads();
    if (t == 0) {
        float S = 0.f, Q = 0.f;
#pragma unroll
        for (int w = 0; w < 4; ++w) { S += s_sum[w]; Q += s_ss[w]; }
        const float mean = S * (1.0f / (float)D_MODEL);
        const float var  = Q * (1.0f / (float)D_MODEL) - mean * mean;
        s_sum[0] = mean;
        s_ss[0]  = rsqrtf(var + LN_EPS);
    }
    __syncthreads();
    const float mean = s_sum[0];
    const float inv  = s_ss[0];

    float4* o4 = (float4*)(out + row_base);
    const float4* g4 = (const float4*)ln_g;
    const float4* b4 = (const float4*)ln_b;
#pragma unroll
    for (int j = 0; j < 2; ++j) {
        const float4 g  = g4[t * 2 + j];
        const float4 bb = b4[t * 2 + j];
        float4 v = h[j];
        float4 r;
        r.x = (v.x - mean) * inv * g.x + bb.x;
        r.y = (v.y - mean) * inv * g.y + bb.y;
        r.z = (v.z - mean) * inv * g.z + bb.z;
        r.w = (v.w - mean) * inv * g.w + bb.w;
        o4[t * 2 + j] = r;
    }
}

extern "C" void kernel_launch(void* const* d_in, const int* in_sizes, int n_in,
                              void* d_out, int out_size, void* d_ws, size_t ws_size,
                              hipStream_t stream) {
    // setup_inputs order: x, gate_w, gate_b, ln_g, ln_b, spine
    const float* x    = (const float*)d_in[0];
    const float* ln_g = (const float*)d_in[3];
    const float* ln_b = (const float*)d_in[4];
    const int*  spine = (const int*)d_in[5];
    float* out = (float*)d_out;

    const long n  = (long)in_sizes[0];          // B*S*D
    const long n4 = n >> 2;                     // float4 count
    const int  K  = in_sizes[5];                // spine length (10)
    const int  B  = (int)(n / ((long)SEQ_LEN * D_MODEL));

    // Full copy: memory-bound, grid-stride float4. 2048 blocks x 256 thr
    // (8 blocks/CU across 256 CUs); 8 float4 per thread at this size.
    copy_kernel<<<2048, 256, 0, stream>>>((const f32x4*)x, (f32x4*)out, n4);

    // Overwrite the B*K spine rows with layernorm(0.5*x_row).
    spine_ln_kernel<<<B * K, 256, 0, stream>>>(x, ln_g, ln_b, spine, out, K);
}

// Round 5
// 246.351 us; speedup vs baseline: 1.0129x; 1.0129x over previous
//
#include <hip/hip_runtime.h>

// PredictionLatticeCore: the gate path (einsum + sigmoid) is algebraically
// dead — x_out = g*h + (1-g)*h == h. Output = x with spine rows replaced by
// layernorm(0.5*x[b,spine,:]) * ln_g + ln_b.
//
// Single fused kernel: one block per row (B*S = 16384 rows, 8 KB each).
// Non-spine rows: nontemporal float4 stream copy. Spine rows (block-uniform
// branch, 20 of 16384): two-pass LN entirely in-block. Saves the second
// launch and its stream serialization vs the round-4 two-kernel version.
//
// Round-4 evidence: dur_us 249.5 includes ~200 us of harness restore/poison
// fills (top-5 dispatches are all fillBufferAligned @ ~80 us, 6.7-6.8 TB/s);
// our controllable slice is the ~50 us copy+LN, floor ~43 us @ 6.3 TB/s.

#define D_MODEL 2048
#define SEQ_LEN 8192
#define LN_EPS 1e-5f

typedef float f32x4 __attribute__((ext_vector_type(4)));

__global__ __launch_bounds__(256) void fused_copy_ln_kernel(
        const float* __restrict__ x,
        const float* __restrict__ ln_g,
        const float* __restrict__ ln_b,
        const int* __restrict__ spine,
        float* __restrict__ out,
        int K) {
    const long r = blockIdx.x;                 // global row, one block per row
    const long base = r * D_MODEL;
    const int  s = (int)(r & (SEQ_LEN - 1));   // position within batch

    // Block-uniform spine membership check (K=10 scalar loads, L2-hot).
    bool is_spine = false;
    for (int k = 0; k < K; ++k) is_spine |= (spine[k] == s);

    const int t = threadIdx.x;                 // 256 threads, 8 floats each
    const f32x4* in4 = (const f32x4*)(x + base);
    f32x4* o4 = (f32x4*)(out + base);

    if (!is_spine) {
        // Coalesced: lane i touches float4 index j*256+i (consecutive 16B).
#pragma unroll
        for (int j = 0; j < 2; ++j) {
            f32x4 v = __builtin_nontemporal_load(&in4[j * 256 + t]);
            __builtin_nontemporal_store(v, &o4[j * 256 + t]);
        }
        return;
    }

    // ---- spine row: layernorm(0.5 * x_row) * ln_g + ln_b ----
    f32x4 h[2];
    float sum = 0.f, ss = 0.f;
#pragma unroll
    for (int j = 0; j < 2; ++j) {
        f32x4 v = in4[j * 256 + t];
        v *= 0.5f;
        h[j] = v;
        sum += v.x + v.y + v.z + v.w;
        ss  += v.x * v.x + v.y * v.y + v.z * v.z + v.w * v.w;
    }

    // wave (64-lane) butterfly reduce, then cross-wave via LDS (4 waves)
#pragma unroll
    for (int off = 32; off > 0; off >>= 1) {
        sum += __shfl_down(sum, off, 64);
        ss  += __shfl_down(ss,  off, 64);
    }
    __shared__ float s_sum[4];
    __shared__ float s_ss[4];
    const int wave = t >> 6;
    const int lane = t & 63;
    if (lane == 0) { s_sum[wave] = sum; s_ss[wave] = ss; }
    __syncthreads();
    if (t == 0) {
        float S = 0.f, Q = 0.f;
#pragma unroll
        for (int w = 0; w < 4; ++w) { S += s_sum[w]; Q += s_ss[w]; }
        const float mean = S * (1.0f / (float)D_MODEL);
        const float var  = Q * (1.0f / (float)D_MODEL) - mean * mean;
        s_sum[0] = mean;
        s_ss[0]  = rsqrtf(var + LN_EPS);
    }
    __syncthreads();
    const float mean = s_sum[0];
    const float inv  = s_ss[0];

    const f32x4* g4 = (const f32x4*)ln_g;
    const f32x4* b4 = (const f32x4*)ln_b;
#pragma unroll
    for (int j = 0; j < 2; ++j) {
        const f32x4 g  = g4[j * 256 + t];
        const f32x4 bb = b4[j * 256 + t];
        f32x4 v = h[j];
        f32x4 rr;
        rr.x = (v.x - mean) * inv * g.x + bb.x;
        rr.y = (v.y - mean) * inv * g.y + bb.y;
        rr.z = (v.z - mean) * inv * g.z + bb.z;
        rr.w = (v.w - mean) * inv * g.w + bb.w;
        o4[j * 256 + t] = rr;
    }
}

extern "C" void kernel_launch(void* const* d_in, const int* in_sizes, int n_in,
                              void* d_out, int out_size, void* d_ws, size_t ws_size,
                              hipStream_t stream) {
    // setup_inputs order: x, gate_w, gate_b, ln_g, ln_b, spine
    const float* x    = (const float*)d_in[0];
    const float* ln_g = (const float*)d_in[3];
    const float* ln_b = (const float*)d_in[4];
    const int*  spine = (const int*)d_in[5];
    float* out = (float*)d_out;

    const long n     = (long)in_sizes[0];       // B*S*D
    const int  K     = in_sizes[5];             // spine length (10)
    const long nrows = n / D_MODEL;             // B*S = 16384

    fused_copy_ln_kernel<<<(int)nrows, 256, 0, stream>>>(x, ln_g, ln_b, spine, out, K);
}